// Round 9
// baseline (1693.973 us; speedup 1.0000x reference)
//
#include <hip/hip_runtime.h>
#include <stdint.h>

// STAR fused forward via split-precision bf16x2 MFMA (gfx950).
// V9 = V8 (M=64, jj=2, aliased dual-plane LDS, 16 waves/CU) with:
//  (a) phase 0 on mfma_f32_32x32x16_bf16: +17% matrix-pipe rate (2382 vs
//      2075 TF ubench) and HALF the MFMA instruction count -> issue relief.
//      W0 + x stored as 32x32-tile B/A fragments (K=16 chunks); epi0 uses
//      the HW-verified 32x32 C/D map col=lane&31,row=(r&3)+8(r>>2)+4(l>>5).
//      Phases 1/2 stay on 16x16x32 with layouts verbatim from V8.
//  (b) prep merged into ONE kernel (ws-prep blocks + x-split blocks) with
//      fully-coalesced x reads (V8's xsplit read at 128B lane stride).
// Bit-identical split math (term grouping changes only the HW accumulate
// order within K=16 vs K=32). Falls back to V1 kernel when ws too small.

namespace {

typedef __attribute__((ext_vector_type(8))) short bf16x8;
typedef __attribute__((ext_vector_type(4))) float f32x4;
typedef __attribute__((ext_vector_type(16))) float f32x16;

union Frag { bf16x8 v; unsigned int u[4]; };

// ws byte layout (L1/L2/biases identical to V1 so the fallback is unchanged)
constexpr size_t WS_L0   = 0;                 // 8j*32kc*8nt pairs * 2048B = 4 MiB
constexpr size_t WS_L1   = 4194304;           // 8*8*8 pairs  * 2048B = 1 MiB
constexpr size_t WS_L2   = 5242880;           // 8*4*4 pairs  * 2048B = 256 KiB
constexpr size_t WS_B0   = 5505024;           // 8*256 f32
constexpr size_t WS_B1   = 5513216;           // 8*128 f32
constexpr size_t WS_B2   = 5517312;           // 8*64  f32
constexpr size_t WS_X    = 5519360;           // 2048 rowblk32 * 32 kc * 2048B = 128 MiB
constexpr size_t WS_TOTAL_BIG = WS_X + (size_t)65536 * 2048; // 139,737,088 B

constexpr int PREP_TOTAL  = 1048576 + 262144 + 65536 + 2048 + 1024 + 512; // 1379840
constexpr int NB_WSPREP   = PREP_TOTAL / 256;   // 5390 blocks (exact)
constexpr int NB_XSPLIT   = 2048;               // one block per 32-row group

__device__ __forceinline__ void splitpair(float a, float b,
                                          unsigned int& hi, unsigned int& lo) {
    unsigned int ua = __float_as_uint(a);
    unsigned int ub = __float_as_uint(b);
    unsigned int ha = ua & 0xffff0000u;
    unsigned int hb = ub & 0xffff0000u;
    float ra = a - __uint_as_float(ha);
    float rb = b - __uint_as_float(hb);
    hi = (ua >> 16) | hb;
    lo = (__float_as_uint(ra) >> 16) | (__float_as_uint(rb) & 0xffff0000u);
}

// scalar split for the dual-plane epilogues (bit-identical to splitpair)
__device__ __forceinline__ void split16(float v, unsigned short& h, unsigned short& l) {
    unsigned int u = __float_as_uint(v);
    h = (unsigned short)(u >> 16);
    float r = v - __uint_as_float(u & 0xffff0000u);
    l = (unsigned short)(__float_as_uint(r) >> 16);
}

// --- plain-bitop versions (fallback kernel keeps these) ---
__device__ __forceinline__ unsigned int packsplit(float v) {
    unsigned int u = __float_as_uint(v);
    unsigned int h = u & 0xffff0000u;
    float r = v - __uint_as_float(h);
    return h | (__float_as_uint(r) >> 16);
}

__device__ __forceinline__ void unpack2(unsigned int e0, unsigned int e1,
                                        unsigned int& hi, unsigned int& lo) {
    hi = (e0 >> 16) | (e1 & 0xffff0000u);
    lo = (e0 & 0xffffu) | (e1 << 16);
}

// ---------------- merged prep kernel ----------------
// blocks [0, NB_WSPREP): fuse sk*dk -> bf16 frag planes + biases.
//   layer 0 layout depends on use32: 32x32 B-frags (main path) or the old
//   16x16 frags (fallback path). layers 1/2 always 16x16 (tails use them).
// blocks [NB_WSPREP, NB_WSPREP+NB_XSPLIT): split x into 32-row A-frag chunks.
//   Chunk (rowblk32, kc16) = 2048B: [hi 1024][lo 1024], lane=(r&31)|(((k>>3)&1)<<5),
//   lane's 16B = k = kc*16 + ((k>>3)&1)*8 + 0..7. Coalesced read AND write.
__global__ __launch_bounds__(256) void prep_all(
        const float* __restrict__ sk0, const float* __restrict__ dk0,
        const float* __restrict__ sk1, const float* __restrict__ dk1,
        const float* __restrict__ sk2, const float* __restrict__ dk2,
        const float* __restrict__ sb0, const float* __restrict__ db0,
        const float* __restrict__ sb1, const float* __restrict__ db1,
        const float* __restrict__ sb2, const float* __restrict__ db2,
        const float* __restrict__ x, char* __restrict__ ws, int use32) {
    __shared__ __align__(16) unsigned int xf[8192];  // 32 KiB (xsplit blocks only)

    if (blockIdx.x < NB_WSPREP) {
        int tid = blockIdx.x * 256 + threadIdx.x;
        if (tid < 1048576) {                       // layer 0: [j][k<512][n<256]
            int n = tid & 255, k = (tid >> 8) & 511, j = tid >> 17;
            float wv = sk0[k * 256 + n] * dk0[(size_t)(j * 512 + k) * 256 + n];
            unsigned int u = __float_as_uint(wv);
            unsigned int h = u & 0xffff0000u;
            float r = wv - __uint_as_float(h);
            int pair, lane;
            if (use32) {   // 32x32 B-frag: tile (kc=k>>4, nt=n>>5)
                pair = (j * 32 + (k >> 4)) * 8 + (n >> 5);
                lane = (n & 31) | (((k >> 3) & 1) << 5);
            } else {       // legacy 16x16 B-frag (fallback kernel)
                pair = (j * 16 + (k >> 5)) * 16 + (n >> 4);
                lane = (n & 15) | (((k >> 3) & 3) << 4);
            }
            size_t off = WS_L0 + (size_t)pair * 2048 + lane * 16 + (k & 7) * 2;
            *(unsigned short*)(ws + off)        = (unsigned short)(u >> 16);
            *(unsigned short*)(ws + off + 1024) = (unsigned short)(__float_as_uint(r) >> 16);
        } else if (tid < 1310720) {                // layer 1: [j][k<256][n<128]
            int t = tid - 1048576;
            int n = t & 127, k = (t >> 7) & 255, j = t >> 15;
            float wv = sk1[k * 128 + n] * dk1[(size_t)(j * 256 + k) * 128 + n];
            unsigned int u = __float_as_uint(wv);
            unsigned int h = u & 0xffff0000u;
            float r = wv - __uint_as_float(h);
            int pair = (j * 8 + (k >> 5)) * 8 + (n >> 4);
            int lane = (n & 15) | (((k >> 3) & 3) << 4);
            size_t off = WS_L1 + (size_t)pair * 2048 + lane * 16 + (k & 7) * 2;
            *(unsigned short*)(ws + off)        = (unsigned short)(u >> 16);
            *(unsigned short*)(ws + off + 1024) = (unsigned short)(__float_as_uint(r) >> 16);
        } else if (tid < 1376256) {                // layer 2: [j][k<128][n<64]
            int t = tid - 1310720;
            int n = t & 63, k = (t >> 6) & 127, j = t >> 13;
            float wv = sk2[k * 64 + n] * dk2[(size_t)(j * 128 + k) * 64 + n];
            unsigned int u = __float_as_uint(wv);
            unsigned int h = u & 0xffff0000u;
            float r = wv - __uint_as_float(h);
            int pair = (j * 4 + (k >> 5)) * 4 + (n >> 4);
            int lane = (n & 15) | (((k >> 3) & 3) << 4);
            size_t off = WS_L2 + (size_t)pair * 2048 + lane * 16 + (k & 7) * 2;
            *(unsigned short*)(ws + off)        = (unsigned short)(u >> 16);
            *(unsigned short*)(ws + off + 1024) = (unsigned short)(__float_as_uint(r) >> 16);
        } else if (tid < 1378304) {                // bias0: 8*256
            int t = tid - 1376256;
            ((float*)(ws + WS_B0))[t] = sb0[t & 255] + db0[t];
        } else if (tid < 1379328) {                // bias1: 8*128
            int t = tid - 1378304;
            ((float*)(ws + WS_B1))[t] = sb1[t & 127] + db1[t];
        } else if (tid < PREP_TOTAL) {             // bias2: 8*64
            int t = tid - 1379328;
            ((float*)(ws + WS_B2))[t] = sb2[t & 63] + db2[t];
        }
    } else {
        // -------- x split: block b covers rows b*32..b*32+31 (64 KB out) ----
        const int b   = blockIdx.x - NB_WSPREP;
        const int tid = threadIdx.x;
        for (int p = 0; p < 2; ++p) {              // k halves 0..255 / 256..511
            if (p) __syncthreads();                // xf reuse hazard
#pragma unroll
            for (int i = 0; i < 4; ++i) {
                const int f  = i * 256 + tid;      // 0..1023
                const int r  = f >> 5;             // local row 0..31
                const int gl = f & 31;             // local k-group (8 floats)
                const float* src = x + ((size_t)b * 32 + r) * 512 + p * 256 + gl * 8;
                float4 a0 = *(const float4*)src;
                float4 a1 = *(const float4*)(src + 4);
                unsigned int hi[4], lo[4];
                splitpair(a0.x, a0.y, hi[0], lo[0]);
                splitpair(a0.z, a0.w, hi[1], lo[1]);
                splitpair(a1.x, a1.y, hi[2], lo[2]);
                splitpair(a1.z, a1.w, hi[3], lo[3]);
                const int kcl  = gl >> 1;
                const int lane = r | ((gl & 1) << 5);
                const int di   = kcl * 512 + lane * 4;     // u32 units
                *(uint4*)&xf[di]       = *(uint4*)hi;
                *(uint4*)&xf[di + 256] = *(uint4*)lo;
            }
            __syncthreads();
            uint4* dst = (uint4*)(ws + WS_X + (size_t)b * 65536 + (size_t)p * 32768) + tid * 8;
#pragma unroll
            for (int i = 0; i < 8; ++i) dst[i] = *(const uint4*)&xf[tid * 32 + i * 4];
        }
    }
}

// ---------------- V9 main kernel: 512 thr (8 waves), 64 rows/block, 1024 blocks
__global__ __launch_bounds__(512, 4) void star_mfma_v9(
    const float* __restrict__ ind,  // [65536,8]
    const char* __restrict__ ws,
    float* __restrict__ out)        // [65536,64]
{
    // 67584B shared buffer. H0 planes live epi0..phase1; H1 planes ALIAS the
    // same memory (H0 dead after phase 1, enforced by the S2 barrier).
    __shared__ __align__(16) char smem[67584];
    unsigned short* const H0hi = (unsigned short*)smem;             // [64][264]
    unsigned short* const H0lo = (unsigned short*)(smem + 33792);   // [64][264]
    unsigned short* const H1hi = (unsigned short*)smem;             // [64][136]
    unsigned short* const H1lo = (unsigned short*)(smem + 33792);   // [64][136]
    __shared__ float indS[8 * 65];

    const int tid  = threadIdx.x;
    const int w    = tid >> 6;      // wave 0..7
    const int lane = tid & 63;
    const int c    = lane & 15;     // 16x16 decomposition (phases 1/2)
    const int q    = lane >> 4;
    const int l31  = lane & 31;     // 32x32 decomposition (phase 0)
    const int lh   = lane >> 5;
    const int bx   = blockIdx.x;
    const int b0   = bx * 64;
    const int mh   = w >> 2;        // phase-2 m-half (rows mh*32..+31)
    const int nt2  = w & 3;         // phase-2 n-tile

    const char* xp  = ws + WS_X;
    const char* wB0 = ws + WS_L0;
    const char* wB1 = ws + WS_L1;
    const char* wB2 = ws + WS_L2;
    const float* bias0 = (const float*)(ws + WS_B0);
    const float* bias1 = (const float*)(ws + WS_B1);
    const float* bias2 = (const float*)(ws + WS_B2);

    // indicator: 64 rows x 8 j, one value per thread; indS[j][m] padded
    indS[(tid & 7) * 65 + (tid >> 3)] = ind[(size_t)b0 * 8 + tid];

    const f32x4 z = {0.f, 0.f, 0.f, 0.f};
    const f32x16 z16 = {0.f, 0.f, 0.f, 0.f, 0.f, 0.f, 0.f, 0.f,
                        0.f, 0.f, 0.f, 0.f, 0.f, 0.f, 0.f, 0.f};
    f32x4 oacc[2]; oacc[0] = z; oacc[1] = z;

    __syncthreads();

    for (int jp = 0; jp < 4; ++jp) {
        // ========== phase 0 (32x32x16) for 2 domains: X[64,512]@W0[512,256]
        // Wave w owns n-cols w*32..+31; mt in {0,1} covers rows. Per kc
        // (K=16): 4 A-loads + 4 B-loads -> 12 MFMAs. acc0 = 64 AGPRs.
        f32x16 acc0[2][2];   // [jj][mt]
#pragma unroll
        for (int jj = 0; jj < 2; ++jj)
#pragma unroll
            for (int mt = 0; mt < 2; ++mt) acc0[jj][mt] = z16;

        for (int kc = 0; kc < 32; ++kc) {
            Frag Ahi[2], Alo[2];
#pragma unroll
            for (int mt = 0; mt < 2; ++mt) {
                const char* ap = xp + ((size_t)((bx * 2 + mt) * 32 + kc) * 2048) + lane * 16;
                *(uint4*)Ahi[mt].u = *(const uint4*)ap;
                *(uint4*)Alo[mt].u = *(const uint4*)(ap + 1024);
            }
#pragma unroll
            for (int jj = 0; jj < 2; ++jj) {
                const int j = jp * 2 + jj;
                const char* pb = wB0 + ((size_t)((j * 32 + kc) * 8 + w) * 2048) + lane * 16;
                Frag Bhi, Blo;
                *(uint4*)Bhi.u = *(const uint4*)pb;
                *(uint4*)Blo.u = *(const uint4*)(pb + 1024);
#pragma unroll
                for (int mt = 0; mt < 2; ++mt) {
                    acc0[jj][mt] = __builtin_amdgcn_mfma_f32_32x32x16_bf16(Ahi[mt].v, Bhi.v, acc0[jj][mt], 0, 0, 0);
                    acc0[jj][mt] = __builtin_amdgcn_mfma_f32_32x32x16_bf16(Ahi[mt].v, Blo.v, acc0[jj][mt], 0, 0, 0);
                    acc0[jj][mt] = __builtin_amdgcn_mfma_f32_32x32x16_bf16(Alo[mt].v, Bhi.v, acc0[jj][mt], 0, 0, 0);
                }
            }
        }

        // ========== per-domain tail: epi0 -> phase1 -> epi1 -> phase2 ======
#pragma unroll
        for (int jj = 0; jj < 2; ++jj) {
            const int j = jp * 2 + jj;

            // epilogue 0: bias + relu -> hi/lo bf16 planes H0[m][k].
            // 32x32 C/D map: col = lane&31, row = (r&3) + 8*(r>>2) + 4*(lane>>5).
            {
                const int col = w * 32 + l31;
                const float bv = bias0[j * 256 + col];
                const int rb = 4 * lh;
#pragma unroll
                for (int mt = 0; mt < 2; ++mt)
#pragma unroll
                    for (int r = 0; r < 16; ++r) {
                        const int row = mt * 32 + (r & 3) + 8 * (r >> 2) + rb;
                        float v = fmaxf(acc0[jj][mt][r] + bv, 0.f);
                        unsigned short h16, l16;
                        split16(v, h16, l16);
                        const int idx = row * 264 + col;
                        H0hi[idx] = h16;
                        H0lo[idx] = l16;
                    }
            }
            __syncthreads();   // S1: H0 writes -> phase-1 reads

            // phase 1 (16x16x32): H0[64,256] @ W1[256,128]; wave w owns cols
            // w*16..+15 for all 64 rows -> zero intra-block B1 duplication.
            f32x4 acc1[4];
#pragma unroll
            for (int mt = 0; mt < 4; ++mt) acc1[mt] = z;
            for (int kc = 0; kc < 8; ++kc) {
                Frag Ahi[4], Alo[4];
#pragma unroll
                for (int mt = 0; mt < 4; ++mt) {
                    const int idx = (mt * 16 + c) * 264 + kc * 32 + q * 8;
                    *(uint4*)Ahi[mt].u = *(const uint4*)&H0hi[idx];
                    *(uint4*)Alo[mt].u = *(const uint4*)&H0lo[idx];
                }
                const char* pb = wB1 + ((size_t)((j * 8 + kc) * 8 + w) * 2048) + lane * 16;
                Frag Bhi, Blo;
                *(uint4*)Bhi.u = *(const uint4*)pb;
                *(uint4*)Blo.u = *(const uint4*)(pb + 1024);
#pragma unroll
                for (int mt = 0; mt < 4; ++mt) {
                    acc1[mt] = __builtin_amdgcn_mfma_f32_16x16x32_bf16(Ahi[mt].v, Bhi.v, acc1[mt], 0, 0, 0);
                    acc1[mt] = __builtin_amdgcn_mfma_f32_16x16x32_bf16(Ahi[mt].v, Blo.v, acc1[mt], 0, 0, 0);
                    acc1[mt] = __builtin_amdgcn_mfma_f32_16x16x32_bf16(Alo[mt].v, Bhi.v, acc1[mt], 0, 0, 0);
                }
            }
            __syncthreads();   // S2: phase-1 H0 reads done BEFORE aliased H1 writes

            // epilogue 1 -> H1 planes (alias H0 memory); col k = w*16 + c
            {
                const int k = w * 16 + c;
                const float bv = bias1[j * 128 + k];
#pragma unroll
                for (int mt = 0; mt < 4; ++mt)
#pragma unroll
                    for (int r = 0; r < 4; ++r) {
                        float v = fmaxf(acc1[mt][r] + bv, 0.f);
                        unsigned short h16, l16;
                        split16(v, h16, l16);
                        const int idx = (mt * 16 + q * 4 + r) * 136 + k;
                        H1hi[idx] = h16;
                        H1lo[idx] = l16;
                    }
            }
            __syncthreads();   // S3: H1 writes -> phase-2 reads

            // phase 2 (16x16x32): H1[64,128] @ W2[128,64]; wave (mh,nt2) owns
            // rows mh*32..+31 x cols nt2*16..+15 (2x B2 dup via L1, minor).
            f32x4 acc2[2]; acc2[0] = z; acc2[1] = z;
            for (int kc = 0; kc < 4; ++kc) {
                const char* pb = wB2 + ((size_t)((j * 4 + kc) * 4 + nt2) * 2048) + lane * 16;
                Frag Bhi, Blo;
                *(uint4*)Bhi.u = *(const uint4*)pb;
                *(uint4*)Blo.u = *(const uint4*)(pb + 1024);
#pragma unroll
                for (int mtl = 0; mtl < 2; ++mtl) {
                    Frag Ahi, Alo;
                    const int idx = ((mh * 2 + mtl) * 16 + c) * 136 + kc * 32 + q * 8;
                    *(uint4*)Ahi.u = *(const uint4*)&H1hi[idx];
                    *(uint4*)Alo.u = *(const uint4*)&H1lo[idx];
                    acc2[mtl] = __builtin_amdgcn_mfma_f32_16x16x32_bf16(Ahi.v, Bhi.v, acc2[mtl], 0, 0, 0);
                    acc2[mtl] = __builtin_amdgcn_mfma_f32_16x16x32_bf16(Ahi.v, Blo.v, acc2[mtl], 0, 0, 0);
                    acc2[mtl] = __builtin_amdgcn_mfma_f32_16x16x32_bf16(Alo.v, Bhi.v, acc2[mtl], 0, 0, 0);
                }
            }
            // epilogue 2: bias + relu + indicator mix into oacc
            {
                const float bv = bias2[j * 64 + nt2 * 16 + c];
#pragma unroll
                for (int mtl = 0; mtl < 2; ++mtl)
#pragma unroll
                    for (int r = 0; r < 4; ++r) {
                        float v = fmaxf(acc2[mtl][r] + bv, 0.f);
                        const int m = (mh * 2 + mtl) * 16 + q * 4 + r;
                        oacc[mtl][r] = fmaf(indS[j * 65 + m], v, oacc[mtl][r]);
                    }
            }
            __syncthreads();   // S4: phase-2 H1 reads done BEFORE next epi0's
                               // aliased H0 writes
        }
    }

    // store: out[b0 + (mh*2+mtl)*16 + q*4 + r][nt2*16 + c]
#pragma unroll
    for (int mtl = 0; mtl < 2; ++mtl)
#pragma unroll
        for (int r = 0; r < 4; ++r)
            out[(size_t)(b0 + (mh * 2 + mtl) * 16 + q * 4 + r) * 64 + nt2 * 16 + c] = oacc[mtl][r];
}

// ---------------- fallback (verbatim V1): 256 thr, splits x on the fly ----
// (uses the legacy 16x16 layer-0 layout -> prep_all launched with use32=0)
__global__ __launch_bounds__(256, 3) void star_mfma_fb(
    const float* __restrict__ x,    // [65536,512]
    const float* __restrict__ ind,  // [65536,8]
    const char* __restrict__ ws,
    float* __restrict__ out)        // [65536,64]
{
    __shared__ unsigned int H0s[32 * 260];
    __shared__ unsigned int H1s[32 * 132];
    __shared__ float indS[8 * 33];

    const int tid  = threadIdx.x;
    const int w    = tid >> 6;
    const int lane = tid & 63;
    const int c    = lane & 15;
    const int q    = lane >> 4;
    const int b0   = blockIdx.x * 32;

    const char* wB0 = ws + WS_L0;
    const char* wB1 = ws + WS_L1;
    const char* wB2 = ws + WS_L2;
    const float* bias0 = (const float*)(ws + WS_B0);
    const float* bias1 = (const float*)(ws + WS_B1);
    const float* bias2 = (const float*)(ws + WS_B2);

    indS[(tid & 7) * 33 + (tid >> 3)] = ind[(size_t)b0 * 8 + tid];

    const f32x4 z = {0.f, 0.f, 0.f, 0.f};
    f32x4 oacc[2]; oacc[0] = z; oacc[1] = z;

    __syncthreads();

    for (int j = 0; j < 8; ++j) {
        f32x4 acc0[2][4];
#pragma unroll
        for (int mt = 0; mt < 2; ++mt)
#pragma unroll
            for (int ntl = 0; ntl < 4; ++ntl) acc0[mt][ntl] = z;

        for (int kc = 0; kc < 16; ++kc) {
            Frag Ahi[2], Alo[2];
#pragma unroll
            for (int mt = 0; mt < 2; ++mt) {
                const float* ap = x + (size_t)(b0 + mt * 16 + c) * 512 + kc * 32 + q * 8;
                float4 a0 = *(const float4*)ap;
                float4 a1 = *(const float4*)(ap + 4);
                splitpair(a0.x, a0.y, Ahi[mt].u[0], Alo[mt].u[0]);
                splitpair(a0.z, a0.w, Ahi[mt].u[1], Alo[mt].u[1]);
                splitpair(a1.x, a1.y, Ahi[mt].u[2], Alo[mt].u[2]);
                splitpair(a1.z, a1.w, Ahi[mt].u[3], Alo[mt].u[3]);
            }
#pragma unroll
            for (int ntl = 0; ntl < 4; ++ntl) {
                const int nt = w * 4 + ntl;
                const char* pb = wB0 + ((size_t)((j * 16 + kc) * 16 + nt) * 2048) + lane * 16;
                Frag Bhi, Blo;
                *(uint4*)Bhi.u = *(const uint4*)pb;
                *(uint4*)Blo.u = *(const uint4*)(pb + 1024);
#pragma unroll
                for (int mt = 0; mt < 2; ++mt) {
                    acc0[mt][ntl] = __builtin_amdgcn_mfma_f32_16x16x32_bf16(Ahi[mt].v, Bhi.v, acc0[mt][ntl], 0, 0, 0);
                    acc0[mt][ntl] = __builtin_amdgcn_mfma_f32_16x16x32_bf16(Ahi[mt].v, Blo.v, acc0[mt][ntl], 0, 0, 0);
                    acc0[mt][ntl] = __builtin_amdgcn_mfma_f32_16x16x32_bf16(Alo[mt].v, Bhi.v, acc0[mt][ntl], 0, 0, 0);
                }
            }
        }
#pragma unroll
        for (int ntl = 0; ntl < 4; ++ntl) {
            const float bv = bias0[j * 256 + w * 64 + ntl * 16 + c];
#pragma unroll
            for (int mt = 0; mt < 2; ++mt)
#pragma unroll
                for (int r = 0; r < 4; ++r) {
                    float v = acc0[mt][ntl][r] + bv;
                    v = fmaxf(v, 0.f);
                    H0s[(mt * 16 + q * 4 + r) * 260 + w * 64 + ntl * 16 + c] = packsplit(v);
                }
        }
        __syncthreads();

        f32x4 acc1[2][2];
#pragma unroll
        for (int mt = 0; mt < 2; ++mt)
#pragma unroll
            for (int ntl = 0; ntl < 2; ++ntl) acc1[mt][ntl] = z;

        for (int kc = 0; kc < 8; ++kc) {
            Frag Ahi[2], Alo[2];
#pragma unroll
            for (int mt = 0; mt < 2; ++mt) {
                const unsigned int* hp = &H0s[(mt * 16 + c) * 260 + kc * 32 + q * 8];
                uint4 e0 = *(const uint4*)hp;
                uint4 e1 = *(const uint4*)(hp + 4);
                unpack2(e0.x, e0.y, Ahi[mt].u[0], Alo[mt].u[0]);
                unpack2(e0.z, e0.w, Ahi[mt].u[1], Alo[mt].u[1]);
                unpack2(e1.x, e1.y, Ahi[mt].u[2], Alo[mt].u[2]);
                unpack2(e1.z, e1.w, Ahi[mt].u[3], Alo[mt].u[3]);
            }
#pragma unroll
            for (int ntl = 0; ntl < 2; ++ntl) {
                const int nt = w * 2 + ntl;
                const char* pb = wB1 + ((size_t)((j * 8 + kc) * 8 + nt) * 2048) + lane * 16;
                Frag Bhi, Blo;
                *(uint4*)Bhi.u = *(const uint4*)pb;
                *(uint4*)Blo.u = *(const uint4*)(pb + 1024);
#pragma unroll
                for (int mt = 0; mt < 2; ++mt) {
                    acc1[mt][ntl] = __builtin_amdgcn_mfma_f32_16x16x32_bf16(Ahi[mt].v, Bhi.v, acc1[mt][ntl], 0, 0, 0);
                    acc1[mt][ntl] = __builtin_amdgcn_mfma_f32_16x16x32_bf16(Ahi[mt].v, Blo.v, acc1[mt][ntl], 0, 0, 0);
                    acc1[mt][ntl] = __builtin_amdgcn_mfma_f32_16x16x32_bf16(Alo[mt].v, Bhi.v, acc1[mt][ntl], 0, 0, 0);
                }
            }
        }
#pragma unroll
        for (int ntl = 0; ntl < 2; ++ntl) {
            const float bv = bias1[j * 128 + w * 32 + ntl * 16 + c];
#pragma unroll
            for (int mt = 0; mt < 2; ++mt)
#pragma unroll
                for (int r = 0; r < 4; ++r) {
                    float v = acc1[mt][ntl][r] + bv;
                    v = fmaxf(v, 0.f);
                    H1s[(mt * 16 + q * 4 + r) * 132 + w * 32 + ntl * 16 + c] = packsplit(v);
                }
        }
        __syncthreads();

        f32x4 acc2[2]; acc2[0] = z; acc2[1] = z;

        for (int kc = 0; kc < 4; ++kc) {
            Frag Ahi[2], Alo[2];
#pragma unroll
            for (int mt = 0; mt < 2; ++mt) {
                const unsigned int* hp = &H1s[(mt * 16 + c) * 132 + kc * 32 + q * 8];
                uint4 e0 = *(const uint4*)hp;
                uint4 e1 = *(const uint4*)(hp + 4);
                unpack2(e0.x, e0.y, Ahi[mt].u[0], Alo[mt].u[0]);
                unpack2(e0.z, e0.w, Ahi[mt].u[1], Alo[mt].u[1]);
                unpack2(e1.x, e1.y, Ahi[mt].u[2], Alo[mt].u[2]);
                unpack2(e1.z, e1.w, Ahi[mt].u[3], Alo[mt].u[3]);
            }
            const char* pb = wB2 + ((size_t)((j * 4 + kc) * 4 + w) * 2048) + lane * 16;
            Frag Bhi, Blo;
            *(uint4*)Bhi.u = *(const uint4*)pb;
            *(uint4*)Blo.u = *(const uint4*)(pb + 1024);
#pragma unroll
            for (int mt = 0; mt < 2; ++mt) {
                acc2[mt] = __builtin_amdgcn_mfma_f32_16x16x32_bf16(Ahi[mt].v, Bhi.v, acc2[mt], 0, 0, 0);
                acc2[mt] = __builtin_amdgcn_mfma_f32_16x16x32_bf16(Ahi[mt].v, Blo.v, acc2[mt], 0, 0, 0);
                acc2[mt] = __builtin_amdgcn_mfma_f32_16x16x32_bf16(Alo[mt].v, Bhi.v, acc2[mt], 0, 0, 0);
            }
        }
        {
            const float bv = bias2[j * 64 + w * 16 + c];
#pragma unroll
            for (int mt = 0; mt < 2; ++mt)
#pragma unroll
                for (int r = 0; r < 4; ++r) {
                    float v = acc2[mt][r] + bv;
                    v = fmaxf(v, 0.f);
                    oacc[mt][r] = fmaf(indS[j * 33 + mt * 16 + q * 4 + r], v, oacc[mt][r]);
                }
        }
    }

#pragma unroll
    for (int mt = 0; mt < 2; ++mt)
#pragma unroll
        for (int r = 0; r < 4; ++r)
            out[(size_t)(b0 + mt * 16 + q * 4 + r) * 64 + w * 16 + c] = oacc[mt][r];
}

} // namespace

extern "C" void kernel_launch(void* const* d_in, const int* in_sizes, int n_in,
                              void* d_out, int out_size, void* d_ws, size_t ws_size,
                              hipStream_t stream) {
    const float* x   = (const float*)d_in[0];
    const float* ind = (const float*)d_in[1];
    const float* sk0 = (const float*)d_in[2];
    const float* sb0 = (const float*)d_in[3];
    const float* dk0 = (const float*)d_in[4];
    const float* db0 = (const float*)d_in[5];
    const float* sk1 = (const float*)d_in[6];
    const float* sb1 = (const float*)d_in[7];
    const float* dk1 = (const float*)d_in[8];
    const float* db1 = (const float*)d_in[9];
    const float* sk2 = (const float*)d_in[10];
    const float* sb2 = (const float*)d_in[11];
    const float* dk2 = (const float*)d_in[12];
    const float* db2 = (const float*)d_in[13];
    char* ws   = (char*)d_ws;
    float* out = (float*)d_out;

    if (ws_size >= WS_TOTAL_BIG) {
        prep_all<<<dim3(NB_WSPREP + NB_XSPLIT), dim3(256), 0, stream>>>(
            sk0, dk0, sk1, dk1, sk2, dk2, sb0, db0, sb1, db1, sb2, db2,
            x, ws, 1);
        star_mfma_v9<<<dim3(1024), dim3(512), 0, stream>>>(ind, ws, out);
    } else {
        prep_all<<<dim3(NB_WSPREP), dim3(256), 0, stream>>>(
            sk0, dk0, sk1, dk1, sk2, dk2, sb0, db0, sb1, db1, sb2, db2,
            x, ws, 0);
        star_mfma_fb<<<dim3(2048), dim3(256), 0, stream>>>(x, ind, ws, out);
    }
}